// Round 12
// baseline (203.556 us; speedup 1.0000x reference)
//
#include <hip/hip_runtime.h>
#include <hip/hip_bf16.h>
#include <stdint.h>

// Problem constants (fixed by the reference)
#define NTOK 32768
#define HDIM 512
#define ODIM 512
#define NEXP 16

// GEMM tile config: R8-exact (best moe: ~49us). TM=64/TN=128/BK=32, 6 blocks/CU,
// XCD swizzle, explicit vmcnt.
#define TM 64
#define TN 128
#define BK 32
#define MTILES 64   // 64 tiles x 64 rows = 4096 tokens/expert capacity (>40 sigma margin)

// counts[e] lives at counts[e*CSTRIDE]: one counter per 128B line -> 16-way parallel L2 atomics
#define CSTRIDE 32

#define GATE_BLKS (NTOK / 16)                      // 2048 gate blocks, 16 tokens each
#define CVT_BLKS (NEXP * ODIM * HDIM / 8 / 256)    // 2048 We-cvt blocks

typedef __bf16 bf16x8 __attribute__((ext_vector_type(8)));
typedef float  floatx4 __attribute__((ext_vector_type(4)));

__device__ __forceinline__ unsigned pk2(unsigned lo, unsigned hi) {
  return (lo >> 16) | (hi & 0xffff0000u);
}

__device__ __forceinline__ bf16x8 asbf8(uint4 u) { bf16x8 v; __builtin_memcpy(&v, &u, 16); return v; }

// exact 3-way bf16 truncation split of 8 floats: f = H + M + L exactly
__device__ __forceinline__ void split3(float4 a, float4 b, uint4* H, uint4* M, uint4* L) {
  float f[8] = {a.x, a.y, a.z, a.w, b.x, b.y, b.z, b.w};
  unsigned h[8], m[8], l[8];
#pragma unroll
  for (int j = 0; j < 8; ++j) {
    union { float F; unsigned U; } u; u.F = f[j];
    h[j] = u.U & 0xffff0000u;
    union { unsigned U; float F; } hv; hv.U = h[j];
    float r1 = f[j] - hv.F;                 // exact
    union { float F; unsigned U; } r1u; r1u.F = r1;
    m[j] = r1u.U & 0xffff0000u;
    union { unsigned U; float F; } mv; mv.U = m[j];
    float r2 = r1 - mv.F;                   // exact, fits bf16
    union { float F; unsigned U; } r2u; r2u.F = r2;
    l[j] = r2u.U;
  }
  H->x = pk2(h[0], h[1]); H->y = pk2(h[2], h[3]); H->z = pk2(h[4], h[5]); H->w = pk2(h[6], h[7]);
  M->x = pk2(m[0], m[1]); M->y = pk2(m[2], m[3]); M->z = pk2(m[4], m[5]); M->w = pk2(m[6], m[7]);
  L->x = pk2(l[0], l[1]); L->y = pk2(l[2], l[3]); L->z = pk2(l[4], l[5]); L->w = pk2(l[6], l[7]);
}

#define GLDS16(g, l) __builtin_amdgcn_global_load_lds( \
    (const __attribute__((address_space(1))) unsigned int*)(g), \
    (__attribute__((address_space(3))) unsigned int*)(l), 16, 0, 0)

// ---------------- fused prep: gate (16 tok/block) + We cvt, 8 blocks/CU, interleaved --
// R11 post-mortem: prep is latency-starved (Occ 22%, VALU 11%, Mfma 3%; floors ~5-7us
// but runs ~50). R12 restores R7's 2048-block 16-token gate and adds:
//  (1) __launch_bounds__(256, 8): VGPR 56<=64, LDS 5.1KB x 8 = 41KB -> 8 blocks/CU
//      resident (32 waves/CU, was effectively 7).
//  (2) gate/cvt interleaved by bid parity (even=gate, odd=cvt; 2048 each) so the
//      memory-streaming cvt blocks co-reside with the latency-bound gate blocks and
//      fill their stall cycles, instead of backfilling after the gate phase.
// Gate math is R7-exact per token -> logits bit-identical (no argmax-flip risk).
__global__ __launch_bounds__(256, 8) void fused_prep(const float* __restrict__ x,
                                                     const float* __restrict__ Wg,
                                                     const float* __restrict__ bg,
                                                     const float* __restrict__ We,
                                                     int* __restrict__ counts,
                                                     int* __restrict__ buckets,
                                                     unsigned short* __restrict__ xbf,
                                                     unsigned short* __restrict__ webf) {
  __shared__ __align__(16) float red[4][16][20];   // [wave][token][expert], stride 20 (5.1KB)

  int bid = blockIdx.x;
  int t = threadIdx.x;
  int pair = bid >> 1;

  if (bid & 1) {
    // ---- We cvt block (odd bids): 8 floats/thread, contiguous ----
    int i = pair * 256 + t;
    const float4* src = (const float4*)We;
    float4 a = src[2 * i];
    float4 b = src[2 * i + 1];
    union { float F; unsigned U; } u[8] = {{a.x},{a.y},{a.z},{a.w},{b.x},{b.y},{b.z},{b.w}};
    uint4 o;
    o.x = pk2(u[0].U, u[1].U); o.y = pk2(u[2].U, u[3].U);
    o.z = pk2(u[4].U, u[5].U); o.w = pk2(u[6].U, u[7].U);
    ((uint4*)webf)[i] = o;
    return;
  }

  // ---- gate block (even bids): 16 tokens ----
  int gid = pair;
  int lane = t & 63;
  int w = t >> 6;               // wave w covers k-range [w*128, w*128+128)
  int tok0 = gid * 16;
  int fr = lane & 15;           // A: token row; B: expert column
  int quad = lane >> 4;         // 8-float chunk within the 32-float k-step

  const float* xb0 = x + (size_t)(tok0 + fr) * HDIM + w * 128 + quad * 8;
  const float* wg0 = Wg + (size_t)fr * HDIM + w * 128 + quad * 8;

  floatx4 acc = {};

  // prefetch si=0 x
  float4 xa = *(const float4*)(xb0);
  float4 xv = *(const float4*)(xb0 + 4);

#pragma unroll
  for (int si = 0; si < 4; ++si) {
    int s = w * 4 + si;
    // B-frags from global (L2-hot 32KB), split in registers — bit-identical to staged path
    float4 wa = *(const float4*)(wg0 + si * 32);
    float4 wb = *(const float4*)(wg0 + si * 32 + 4);
    uint4 BH, BM, BL;
    split3(wa, wb, &BH, &BM, &BL);
    bf16x8 bh = asbf8(BH), bm = asbf8(BM), bl = asbf8(BL);

    float4 nxa, nxv;
    if (si < 3) {
      nxa = *(const float4*)(xb0 + (si + 1) * 32);
      nxv = *(const float4*)(xb0 + (si + 1) * 32 + 4);
    }

    uint4 H, M, L;
    split3(xa, xv, &H, &M, &L);
    *(uint4*)(xbf + (size_t)(tok0 + fr) * HDIM + s * 32 + quad * 8) = H;  // fused x->bf16
    bf16x8 ah = asbf8(H), am = asbf8(M), al = asbf8(L);
    acc = __builtin_amdgcn_mfma_f32_16x16x32_bf16(ah, bh, acc, 0, 0, 0);
    acc = __builtin_amdgcn_mfma_f32_16x16x32_bf16(ah, bm, acc, 0, 0, 0);
    acc = __builtin_amdgcn_mfma_f32_16x16x32_bf16(am, bh, acc, 0, 0, 0);
    acc = __builtin_amdgcn_mfma_f32_16x16x32_bf16(am, bm, acc, 0, 0, 0);
    acc = __builtin_amdgcn_mfma_f32_16x16x32_bf16(ah, bl, acc, 0, 0, 0);
    acc = __builtin_amdgcn_mfma_f32_16x16x32_bf16(al, bh, acc, 0, 0, 0);
    acc = __builtin_amdgcn_mfma_f32_16x16x32_bf16(am, bl, acc, 0, 0, 0);
    acc = __builtin_amdgcn_mfma_f32_16x16x32_bf16(al, bm, acc, 0, 0, 0);

    if (si < 3) { xa = nxa; xv = nxv; }
  }

  // cross-wave reduction: C/D layout col(lane&15)=expert, row=quad*4+i=token
#pragma unroll
  for (int i = 0; i < 4; ++i)
    red[w][quad * 4 + i][fr] = acc[i];
  __syncthreads();

  if (t < 16) {
    int r = t;    // token row
    float4 tot4[4];
#pragma unroll
    for (int eq = 0; eq < 4; ++eq) tot4[eq] = *(const float4*)&bg[eq * 4];
#pragma unroll
    for (int ww = 0; ww < 4; ++ww)
#pragma unroll
      for (int eq = 0; eq < 4; ++eq) {
        float4 v = *(const float4*)&red[ww][r][eq * 4];
        tot4[eq].x += v.x; tot4[eq].y += v.y; tot4[eq].z += v.z; tot4[eq].w += v.w;
      }
    float tot[16];
#pragma unroll
    for (int eq = 0; eq < 4; ++eq) {
      tot[eq * 4 + 0] = tot4[eq].x; tot[eq * 4 + 1] = tot4[eq].y;
      tot[eq * 4 + 2] = tot4[eq].z; tot[eq * 4 + 3] = tot4[eq].w;
    }
    float bv = tot[0]; int bi = 0;
#pragma unroll
    for (int e = 1; e < NEXP; ++e) if (tot[e] > bv) { bv = tot[e]; bi = e; }  // numpy first-index tie-break

    int token = tok0 + r;
    // staggered expert order: blocks hit different counters at any instant
    for (int ee = 0; ee < NEXP; ++ee) {
      int e = (ee + gid) & 15;
      unsigned long long mask = __ballot(bi == e);   // only lanes t<16 active
      if (mask) {
        int leader = __builtin_ctzll(mask);
        int base = 0;
        if (lane == leader) base = atomicAdd(&counts[e << 5], (int)__popcll(mask));
        base = __shfl(base, leader, 64);
        if (bi == e) {
          int rank = (int)__popcll(mask & ((1ull << lane) - 1ull));
          buckets[e * NTOK + base + rank] = token;
        }
      }
    }
  }
}

// ---------------- gathered-A GEMM, R8-exact (frozen best: ~49us) ----------------
// 4096 blocks, bijective XCD swizzle: swz = (lin&7)*512 + (lin>>3) -> each XCD gets 512
// consecutive items = 2 full experts; expert working set (B 512KB + A ~2MB) fits the
// 4MB per-XCD L2 (R8: FETCH 53->29MB verified). One barrier per k-iter; glds for k+1
// issued after barrier k; explicit vmcnt(0) drain; 6 blocks/CU.
//
// LDS layout per R-row x 32 tile: cell(pair, slot), byte = pair*128 + slot*16,
// pair = row>>1, slot = (((row&1)<<2)|c) ^ (pair&7), c = 16B k-chunk. glds dest
// linear; inverse swizzle on the per-lane GLOBAL source (rule #21). Fragment
// ds_read_b128 = 2 lanes/bank (free, m136).
__global__ __launch_bounds__(256, 6) void moe_gemm(const unsigned short* __restrict__ xbf,
                                                   const unsigned short* __restrict__ webf,
                                                   const float* __restrict__ be,
                                                   const int* __restrict__ counts,
                                                   const int* __restrict__ buckets,
                                                   float* __restrict__ out) {
  int lin = blockIdx.x;
  int swz = (lin & 7) * 512 + (lin >> 3);   // XCD-contiguous work id (bijective, 4096%8==0)
  int e = swz >> 8;                          // 256 work items per expert
  int rem = swz & 255;
  int o0 = (rem >> 6) * TN;                  // 4 n-tiles
  int m0 = (rem & 63) * TM;                  // 64 m-tiles

  int cnt = counts[e << 5];
  if (m0 >= cnt) return;

  __shared__ __align__(16) unsigned short As[2][TM * BK];   // 2 x 4 KB
  __shared__ __align__(16) unsigned short Bs[2][TN * BK];   // 2 x 8 KB
  __shared__ int toks[TM];

  int t = threadIdx.x;
  int lane = t & 63;
  int w = t >> 6;

  if (t < TM) {
    int r = m0 + t;
    toks[t] = (r < cnt) ? buckets[e * NTOK + r] : buckets[e * NTOK];
  }
  __syncthreads();

  // staging decode: one glds covers 16 rows x 4 chunks = 64 lanes.
  int pl = lane >> 3;
  int sl = lane & 7;
  int slog = sl ^ pl;
  int rsub = 2 * pl + (slog >> 2);
  int cch = slog & 3;

  // A: wave w stages rows w*16 .. w*16+15 (1 glds)
  const unsigned short* agp = xbf + (size_t)toks[w * 16 + rsub] * HDIM + cch * 8;
  // B: wave w stages rows w*32+j*16 .. +15, j=0,1 (2 glds)
  const unsigned short* bgp[2];
#pragma unroll
  for (int j = 0; j < 2; ++j) {
    int row = w * 32 + j * 16 + rsub;
    bgp[j] = webf + ((size_t)e * ODIM + o0 + row) * HDIM + cch * 8;
  }

  int wm = (w & 1) * 32;        // 2 m-halves of 32
  int wn = (w >> 1) * 64;       // 2 n-halves of 64
  int fr = lane & 15;
  int quad = lane >> 4;

  int aoff[2], boff[4];
#pragma unroll
  for (int mt = 0; mt < 2; ++mt) {
    int m = wm + mt * 16 + fr;
    int pr = m >> 1;
    aoff[mt] = pr * 64 + (((((m & 1) << 2) | quad) ^ (pr & 7)) << 3);
  }
#pragma unroll
  for (int nt = 0; nt < 4; ++nt) {
    int n = wn + nt * 16 + fr;
    int pn = n >> 1;
    boff[nt] = pn * 64 + (((((n & 1) << 2) | quad) ^ (pn & 7)) << 3);
  }

  // hoist bias loads: complete long before the epilogue needs them
  float bias[4];
#pragma unroll
  for (int nt = 0; nt < 4; ++nt)
    bias[nt] = be[e * ODIM + o0 + wn + nt * 16 + fr];

  floatx4 acc[2][4] = {};

  // prologue: fill buffer 0 (k=0)
  GLDS16(agp, As[0] + w * 512);
#pragma unroll
  for (int j = 0; j < 2; ++j)
    GLDS16(bgp[j], Bs[0] + w * 1024 + j * 512);

  for (int k = 0; k < HDIM / BK; ++k) {
    int p = k & 1;
    // explicit drain: all of this wave's outstanding glds writes landed in LDS
    asm volatile("s_waitcnt vmcnt(0)" ::: "memory");
    __syncthreads();   // buf p ready everywhere; buf 1-p reads (iter k-1) done
    if (k < HDIM / BK - 1) {
      int koff = (k + 1) * BK;
      GLDS16(agp + koff, As[1 - p] + w * 512);
#pragma unroll
      for (int j = 0; j < 2; ++j)
        GLDS16(bgp[j] + koff, Bs[1 - p] + w * 1024 + j * 512);
    }

    bf16x8 af[2], bfr[4];
#pragma unroll
    for (int mt = 0; mt < 2; ++mt)
      af[mt] = *(const bf16x8*)(As[p] + aoff[mt]);
#pragma unroll
    for (int nt = 0; nt < 4; ++nt)
      bfr[nt] = *(const bf16x8*)(Bs[p] + boff[nt]);
#pragma unroll
    for (int mt = 0; mt < 2; ++mt)
#pragma unroll
      for (int nt = 0; nt < 4; ++nt)
        acc[mt][nt] = __builtin_amdgcn_mfma_f32_16x16x32_bf16(af[mt], bfr[nt], acc[mt][nt], 0, 0, 0);
  }

  // epilogue: C/D layout col=lane&15, row=quad*4+i
  int rbase = wm + quad * 4;
#pragma unroll
  for (int nt = 0; nt < 4; ++nt) {
    int col = o0 + wn + nt * 16 + fr;
#pragma unroll
    for (int mt = 0; mt < 2; ++mt) {
#pragma unroll
      for (int i = 0; i < 4; ++i) {
        int rl = rbase + mt * 16 + i;
        if (m0 + rl < cnt) {
          out[(size_t)toks[rl] * ODIM + col] = acc[mt][nt][i] + bias[nt];
        }
      }
    }
  }
}

// ---------------- launch ----------------
// ws layout: [0, 2KB) strided counts | [4KB, +2MB) buckets | xbf 32MB | webf 8MB
#define WS_BUCKETS 4096
#define WS_XBF (WS_BUCKETS + NEXP * NTOK * 4)
#define WS_WEBF (WS_XBF + NTOK * HDIM * 2)

extern "C" void kernel_launch(void* const* d_in, const int* in_sizes, int n_in,
                              void* d_out, int out_size, void* d_ws, size_t ws_size,
                              hipStream_t stream) {
  const float* x  = (const float*)d_in[0];
  const float* Wg = (const float*)d_in[1];
  const float* bg = (const float*)d_in[2];
  const float* We = (const float*)d_in[3];
  const float* be = (const float*)d_in[4];
  float* out = (float*)d_out;
  char* ws = (char*)d_ws;

  int* counts = (int*)ws;
  int* buckets = (int*)(ws + WS_BUCKETS);
  unsigned short* xbf  = (unsigned short*)(ws + WS_XBF);
  unsigned short* webf = (unsigned short*)(ws + WS_WEBF);

  (void)hipMemsetAsync(counts, 0, NEXP * CSTRIDE * 4, stream);
  fused_prep<<<GATE_BLKS + CVT_BLKS, 256, 0, stream>>>(x, Wg, bg, We, counts, buckets, xbf, webf);
  moe_gemm<<<MTILES * (ODIM / TN) * NEXP, 256, 0, stream>>>(xbf, webf, be, counts, buckets, out);
}

// Round 13
// 189.168 us; speedup vs baseline: 1.0761x; 1.0761x over previous
//
#include <hip/hip_runtime.h>
#include <hip/hip_bf16.h>
#include <stdint.h>

// Problem constants (fixed by the reference)
#define NTOK 32768
#define HDIM 512
#define ODIM 512
#define NEXP 16

// GEMM tile config: R8-exact (best moe: ~49us). TM=64/TN=128/BK=32, 6 blocks/CU,
// XCD swizzle, explicit vmcnt.
#define TM 64
#define TN 128
#define BK 32
#define MTILES 64   // 64 tiles x 64 rows = 4096 tokens/expert capacity (>40 sigma margin)

// counts[e] lives at counts[e*CSTRIDE]: one counter per 128B line -> 16-way parallel L2 atomics
#define CSTRIDE 32

#define GATE_BLKS (NTOK / 16)                      // 2048 gate blocks, 16 tokens each
#define CVT_BLKS (NEXP * ODIM * HDIM / 8 / 256)    // 2048 We-cvt blocks

typedef __bf16 bf16x8 __attribute__((ext_vector_type(8)));
typedef float  floatx4 __attribute__((ext_vector_type(4)));

__device__ __forceinline__ unsigned pk2(unsigned lo, unsigned hi) {
  return (lo >> 16) | (hi & 0xffff0000u);
}

__device__ __forceinline__ bf16x8 asbf8(uint4 u) { bf16x8 v; __builtin_memcpy(&v, &u, 16); return v; }

// exact 3-way bf16 truncation split of 8 floats: f = H + M + L exactly
__device__ __forceinline__ void split3(float4 a, float4 b, uint4* H, uint4* M, uint4* L) {
  float f[8] = {a.x, a.y, a.z, a.w, b.x, b.y, b.z, b.w};
  unsigned h[8], m[8], l[8];
#pragma unroll
  for (int j = 0; j < 8; ++j) {
    union { float F; unsigned U; } u; u.F = f[j];
    h[j] = u.U & 0xffff0000u;
    union { unsigned U; float F; } hv; hv.U = h[j];
    float r1 = f[j] - hv.F;                 // exact
    union { float F; unsigned U; } r1u; r1u.F = r1;
    m[j] = r1u.U & 0xffff0000u;
    union { unsigned U; float F; } mv; mv.U = m[j];
    float r2 = r1 - mv.F;                   // exact, fits bf16
    union { float F; unsigned U; } r2u; r2u.F = r2;
    l[j] = r2u.U;
  }
  H->x = pk2(h[0], h[1]); H->y = pk2(h[2], h[3]); H->z = pk2(h[4], h[5]); H->w = pk2(h[6], h[7]);
  M->x = pk2(m[0], m[1]); M->y = pk2(m[2], m[3]); M->z = pk2(m[4], m[5]); M->w = pk2(m[6], m[7]);
  L->x = pk2(l[0], l[1]); L->y = pk2(l[2], l[3]); L->z = pk2(l[4], l[5]); L->w = pk2(l[6], l[7]);
}

#define GLDS16(g, l) __builtin_amdgcn_global_load_lds( \
    (const __attribute__((address_space(1))) unsigned int*)(g), \
    (__attribute__((address_space(3))) unsigned int*)(l), 16, 0, 0)

// ---------------- wg_prep: split Wg once + zero counts (replaces hipMemsetAsync) ------
// 4 blocks x 256 threads x 8 floats = 8192 = 16x512. Output: 3 bf16 [16][512] streams
// (wgh/wgm/wgl, 16KB each, L2-resident). Same split3 code as the gate used inline ->
// bit-identical frags; gate now LOADS them instead of recomputing (the Wg split3 was
// ~40% of the gate's serial VALU chain, re-done by all 2048 blocks x 4 si).
__global__ __launch_bounds__(256) void wg_prep(const float* __restrict__ Wg,
                                               unsigned short* __restrict__ wgh,
                                               unsigned short* __restrict__ wgm,
                                               unsigned short* __restrict__ wgl,
                                               int* __restrict__ counts) {
  int t = threadIdx.x;
  int i = blockIdx.x * 256 + t;
  if (blockIdx.x == 0) {
    ((int2*)counts)[t] = make_int2(0, 0);   // 256 x 8B = 2KB = NEXP*CSTRIDE*4
  }
  const float4* src = (const float4*)Wg;
  float4 a = src[2 * i];
  float4 b = src[2 * i + 1];
  uint4 H, M, L;
  split3(a, b, &H, &M, &L);
  ((uint4*)wgh)[i] = H;
  ((uint4*)wgm)[i] = M;
  ((uint4*)wgl)[i] = L;
}

// ---------------- fused prep: gate (16 tok/block) + We fp32->bf16 cvt ----------------
// R8 structure (bounds(256,4), gate blocks first, cvt appended). Single change vs R8:
// B-frags (bh/bm/bl) are LOADED from the precomputed wgh/wgm/wgl streams (3 x 16B from
// L2) instead of 2 float4 loads + ~25-op serial split3 per si. Logits bit-identical.
__global__ __launch_bounds__(256, 4) void fused_prep(const float* __restrict__ x,
                                                     const unsigned short* __restrict__ wgh,
                                                     const unsigned short* __restrict__ wgm,
                                                     const unsigned short* __restrict__ wgl,
                                                     const float* __restrict__ bg,
                                                     const float* __restrict__ We,
                                                     int* __restrict__ counts,
                                                     int* __restrict__ buckets,
                                                     unsigned short* __restrict__ xbf,
                                                     unsigned short* __restrict__ webf) {
  __shared__ __align__(16) float red[4][16][20];   // [wave][token][expert], stride 20

  int bid = blockIdx.x;
  int t = threadIdx.x;

  if (bid >= GATE_BLKS) {
    // ---- We cvt block: 8 floats/thread, contiguous ----
    int i = (bid - GATE_BLKS) * 256 + t;
    const float4* src = (const float4*)We;
    float4 a = src[2 * i];
    float4 b = src[2 * i + 1];
    union { float F; unsigned U; } u[8] = {{a.x},{a.y},{a.z},{a.w},{b.x},{b.y},{b.z},{b.w}};
    uint4 o;
    o.x = pk2(u[0].U, u[1].U); o.y = pk2(u[2].U, u[3].U);
    o.z = pk2(u[4].U, u[5].U); o.w = pk2(u[6].U, u[7].U);
    ((uint4*)webf)[i] = o;
    return;
  }

  // ---- gate block: 16 tokens ----
  int lane = t & 63;
  int w = t >> 6;               // wave w covers k-range [w*128, w*128+128)
  int tok0 = bid * 16;
  int fr = lane & 15;           // A: token row; B: expert column
  int quad = lane >> 4;         // 8-float chunk within the 32-float k-step

  const float* xb0 = x + (size_t)(tok0 + fr) * HDIM + w * 128 + quad * 8;
  size_t wgo = (size_t)fr * HDIM + w * 128 + quad * 8;   // element offset into [16][512]

  floatx4 acc = {};

  // prefetch si=0 x
  float4 xa = *(const float4*)(xb0);
  float4 xv = *(const float4*)(xb0 + 4);

#pragma unroll
  for (int si = 0; si < 4; ++si) {
    int s = w * 4 + si;
    // B-frags: precomputed split streams, L2-hot (3 x 16B loads, no VALU chain)
    bf16x8 bh = *(const bf16x8*)(wgh + wgo + si * 32);
    bf16x8 bm = *(const bf16x8*)(wgm + wgo + si * 32);
    bf16x8 bl = *(const bf16x8*)(wgl + wgo + si * 32);

    float4 nxa, nxv;
    if (si < 3) {
      nxa = *(const float4*)(xb0 + (si + 1) * 32);
      nxv = *(const float4*)(xb0 + (si + 1) * 32 + 4);
    }

    uint4 H, M, L;
    split3(xa, xv, &H, &M, &L);
    *(uint4*)(xbf + (size_t)(tok0 + fr) * HDIM + s * 32 + quad * 8) = H;  // fused x->bf16
    bf16x8 ah = asbf8(H), am = asbf8(M), al = asbf8(L);
    acc = __builtin_amdgcn_mfma_f32_16x16x32_bf16(ah, bh, acc, 0, 0, 0);
    acc = __builtin_amdgcn_mfma_f32_16x16x32_bf16(ah, bm, acc, 0, 0, 0);
    acc = __builtin_amdgcn_mfma_f32_16x16x32_bf16(am, bh, acc, 0, 0, 0);
    acc = __builtin_amdgcn_mfma_f32_16x16x32_bf16(am, bm, acc, 0, 0, 0);
    acc = __builtin_amdgcn_mfma_f32_16x16x32_bf16(ah, bl, acc, 0, 0, 0);
    acc = __builtin_amdgcn_mfma_f32_16x16x32_bf16(al, bh, acc, 0, 0, 0);
    acc = __builtin_amdgcn_mfma_f32_16x16x32_bf16(am, bl, acc, 0, 0, 0);
    acc = __builtin_amdgcn_mfma_f32_16x16x32_bf16(al, bm, acc, 0, 0, 0);

    if (si < 3) { xa = nxa; xv = nxv; }
  }

  // cross-wave reduction: C/D layout col(lane&15)=expert, row=quad*4+i=token
#pragma unroll
  for (int i = 0; i < 4; ++i)
    red[w][quad * 4 + i][fr] = acc[i];
  __syncthreads();

  if (t < 16) {
    int r = t;    // token row
    float4 tot4[4];
#pragma unroll
    for (int eq = 0; eq < 4; ++eq) tot4[eq] = *(const float4*)&bg[eq * 4];
#pragma unroll
    for (int ww = 0; ww < 4; ++ww)
#pragma unroll
      for (int eq = 0; eq < 4; ++eq) {
        float4 v = *(const float4*)&red[ww][r][eq * 4];
        tot4[eq].x += v.x; tot4[eq].y += v.y; tot4[eq].z += v.z; tot4[eq].w += v.w;
      }
    float tot[16];
#pragma unroll
    for (int eq = 0; eq < 4; ++eq) {
      tot[eq * 4 + 0] = tot4[eq].x; tot[eq * 4 + 1] = tot4[eq].y;
      tot[eq * 4 + 2] = tot4[eq].z; tot[eq * 4 + 3] = tot4[eq].w;
    }
    float bv = tot[0]; int bi = 0;
#pragma unroll
    for (int e = 1; e < NEXP; ++e) if (tot[e] > bv) { bv = tot[e]; bi = e; }  // numpy first-index tie-break

    int token = tok0 + r;
    // staggered expert order: blocks hit different counters at any instant
    for (int ee = 0; ee < NEXP; ++ee) {
      int e = (ee + bid) & 15;
      unsigned long long mask = __ballot(bi == e);   // only lanes t<16 active
      if (mask) {
        int leader = __builtin_ctzll(mask);
        int base = 0;
        if (lane == leader) base = atomicAdd(&counts[e << 5], (int)__popcll(mask));
        base = __shfl(base, leader, 64);
        if (bi == e) {
          int rank = (int)__popcll(mask & ((1ull << lane) - 1ull));
          buckets[e * NTOK + base + rank] = token;
        }
      }
    }
  }
}

// ---------------- gathered-A GEMM, R8-exact (frozen best: ~49us) ----------------
// 4096 blocks, bijective XCD swizzle: swz = (lin&7)*512 + (lin>>3) -> each XCD gets 512
// consecutive items = 2 full experts; expert working set (B 512KB + A ~2MB) fits the
// 4MB per-XCD L2 (R8: FETCH 53->29MB verified). One barrier per k-iter; glds for k+1
// issued after barrier k; explicit vmcnt(0) drain; 6 blocks/CU.
//
// LDS layout per R-row x 32 tile: cell(pair, slot), byte = pair*128 + slot*16,
// pair = row>>1, slot = (((row&1)<<2)|c) ^ (pair&7), c = 16B k-chunk. glds dest
// linear; inverse swizzle on the per-lane GLOBAL source (rule #21). Fragment
// ds_read_b128 = 2 lanes/bank (free, m136).
__global__ __launch_bounds__(256, 6) void moe_gemm(const unsigned short* __restrict__ xbf,
                                                   const unsigned short* __restrict__ webf,
                                                   const float* __restrict__ be,
                                                   const int* __restrict__ counts,
                                                   const int* __restrict__ buckets,
                                                   float* __restrict__ out) {
  int lin = blockIdx.x;
  int swz = (lin & 7) * 512 + (lin >> 3);   // XCD-contiguous work id (bijective, 4096%8==0)
  int e = swz >> 8;                          // 256 work items per expert
  int rem = swz & 255;
  int o0 = (rem >> 6) * TN;                  // 4 n-tiles
  int m0 = (rem & 63) * TM;                  // 64 m-tiles

  int cnt = counts[e << 5];
  if (m0 >= cnt) return;

  __shared__ __align__(16) unsigned short As[2][TM * BK];   // 2 x 4 KB
  __shared__ __align__(16) unsigned short Bs[2][TN * BK];   // 2 x 8 KB
  __shared__ int toks[TM];

  int t = threadIdx.x;
  int lane = t & 63;
  int w = t >> 6;

  if (t < TM) {
    int r = m0 + t;
    toks[t] = (r < cnt) ? buckets[e * NTOK + r] : buckets[e * NTOK];
  }
  __syncthreads();

  // staging decode: one glds covers 16 rows x 4 chunks = 64 lanes.
  int pl = lane >> 3;
  int sl = lane & 7;
  int slog = sl ^ pl;
  int rsub = 2 * pl + (slog >> 2);
  int cch = slog & 3;

  // A: wave w stages rows w*16 .. w*16+15 (1 glds)
  const unsigned short* agp = xbf + (size_t)toks[w * 16 + rsub] * HDIM + cch * 8;
  // B: wave w stages rows w*32+j*16 .. +15, j=0,1 (2 glds)
  const unsigned short* bgp[2];
#pragma unroll
  for (int j = 0; j < 2; ++j) {
    int row = w * 32 + j * 16 + rsub;
    bgp[j] = webf + ((size_t)e * ODIM + o0 + row) * HDIM + cch * 8;
  }

  int wm = (w & 1) * 32;        // 2 m-halves of 32
  int wn = (w >> 1) * 64;       // 2 n-halves of 64
  int fr = lane & 15;
  int quad = lane >> 4;

  int aoff[2], boff[4];
#pragma unroll
  for (int mt = 0; mt < 2; ++mt) {
    int m = wm + mt * 16 + fr;
    int pr = m >> 1;
    aoff[mt] = pr * 64 + (((((m & 1) << 2) | quad) ^ (pr & 7)) << 3);
  }
#pragma unroll
  for (int nt = 0; nt < 4; ++nt) {
    int n = wn + nt * 16 + fr;
    int pn = n >> 1;
    boff[nt] = pn * 64 + (((((n & 1) << 2) | quad) ^ (pn & 7)) << 3);
  }

  // hoist bias loads: complete long before the epilogue needs them
  float bias[4];
#pragma unroll
  for (int nt = 0; nt < 4; ++nt)
    bias[nt] = be[e * ODIM + o0 + wn + nt * 16 + fr];

  floatx4 acc[2][4] = {};

  // prologue: fill buffer 0 (k=0)
  GLDS16(agp, As[0] + w * 512);
#pragma unroll
  for (int j = 0; j < 2; ++j)
    GLDS16(bgp[j], Bs[0] + w * 1024 + j * 512);

  for (int k = 0; k < HDIM / BK; ++k) {
    int p = k & 1;
    // explicit drain: all of this wave's outstanding glds writes landed in LDS
    asm volatile("s_waitcnt vmcnt(0)" ::: "memory");
    __syncthreads();   // buf p ready everywhere; buf 1-p reads (iter k-1) done
    if (k < HDIM / BK - 1) {
      int koff = (k + 1) * BK;
      GLDS16(agp + koff, As[1 - p] + w * 512);
#pragma unroll
      for (int j = 0; j < 2; ++j)
        GLDS16(bgp[j] + koff, Bs[1 - p] + w * 1024 + j * 512);
    }

    bf16x8 af[2], bfr[4];
#pragma unroll
    for (int mt = 0; mt < 2; ++mt)
      af[mt] = *(const bf16x8*)(As[p] + aoff[mt]);
#pragma unroll
    for (int nt = 0; nt < 4; ++nt)
      bfr[nt] = *(const bf16x8*)(Bs[p] + boff[nt]);
#pragma unroll
    for (int mt = 0; mt < 2; ++mt)
#pragma unroll
      for (int nt = 0; nt < 4; ++nt)
        acc[mt][nt] = __builtin_amdgcn_mfma_f32_16x16x32_bf16(af[mt], bfr[nt], acc[mt][nt], 0, 0, 0);
  }

  // epilogue: C/D layout col=lane&15, row=quad*4+i
  int rbase = wm + quad * 4;
#pragma unroll
  for (int nt = 0; nt < 4; ++nt) {
    int col = o0 + wn + nt * 16 + fr;
#pragma unroll
    for (int mt = 0; mt < 2; ++mt) {
#pragma unroll
      for (int i = 0; i < 4; ++i) {
        int rl = rbase + mt * 16 + i;
        if (m0 + rl < cnt) {
          out[(size_t)toks[rl] * ODIM + col] = acc[mt][nt][i] + bias[nt];
        }
      }
    }
  }
}

// ---------------- launch ----------------
// ws layout: [0, 2KB) strided counts | [4KB, +2MB) buckets | xbf 32MB | webf 8MB |
//            wgh/wgm/wgl 3 x 16KB
#define WS_BUCKETS 4096
#define WS_XBF (WS_BUCKETS + NEXP * NTOK * 4)
#define WS_WEBF (WS_XBF + NTOK * HDIM * 2)
#define WS_WGH (WS_WEBF + NEXP * ODIM * HDIM * 2)
#define WS_WGM (WS_WGH + NEXP * HDIM * 2)
#define WS_WGL (WS_WGM + NEXP * HDIM * 2)

extern "C" void kernel_launch(void* const* d_in, const int* in_sizes, int n_in,
                              void* d_out, int out_size, void* d_ws, size_t ws_size,
                              hipStream_t stream) {
  const float* x  = (const float*)d_in[0];
  const float* Wg = (const float*)d_in[1];
  const float* bg = (const float*)d_in[2];
  const float* We = (const float*)d_in[3];
  const float* be = (const float*)d_in[4];
  float* out = (float*)d_out;
  char* ws = (char*)d_ws;

  int* counts = (int*)ws;
  int* buckets = (int*)(ws + WS_BUCKETS);
  unsigned short* xbf  = (unsigned short*)(ws + WS_XBF);
  unsigned short* webf = (unsigned short*)(ws + WS_WEBF);
  unsigned short* wgh  = (unsigned short*)(ws + WS_WGH);
  unsigned short* wgm  = (unsigned short*)(ws + WS_WGM);
  unsigned short* wgl  = (unsigned short*)(ws + WS_WGL);

  wg_prep<<<4, 256, 0, stream>>>(Wg, wgh, wgm, wgl, counts);   // also zeros counts
  fused_prep<<<GATE_BLKS + CVT_BLKS, 256, 0, stream>>>(x, wgh, wgm, wgl, bg, We,
                                                       counts, buckets, xbf, webf);
  moe_gemm<<<MTILES * (ODIM / TN) * NEXP, 256, 0, stream>>>(xbf, webf, be, counts, buckets, out);
}

// Round 14
// 187.008 us; speedup vs baseline: 1.0885x; 1.0115x over previous
//
#include <hip/hip_runtime.h>
#include <hip/hip_bf16.h>
#include <stdint.h>

// Problem constants (fixed by the reference)
#define NTOK 32768
#define HDIM 512
#define ODIM 512
#define NEXP 16

// GEMM tile config: R8-exact (best measured total: 186.9us).
// TM=64/TN=128/BK=32, 6 blocks/CU, XCD swizzle, explicit vmcnt.
// Falsified levers (R3-R13): pipeline depth, no-LDS fragments, TM=128, atomics,
// occupancy (3x confirmations), Wg-split hoist. Confirmed: XCD swizzle (FETCH 53->29MB),
// cvt fusion, 4-6 blocks/CU.
#define TM 64
#define TN 128
#define BK 32
#define MTILES 64   // 64 tiles x 64 rows = 4096 tokens/expert capacity (>40 sigma margin)

// counts[e] lives at counts[e*CSTRIDE]: one counter per 128B line -> 16-way parallel L2 atomics
#define CSTRIDE 32

#define GATE_BLKS (NTOK / 16)                      // 2048 gate blocks, 16 tokens each
#define CVT_BLKS (NEXP * ODIM * HDIM / 8 / 256)    // 2048 We-cvt blocks

typedef __bf16 bf16x8 __attribute__((ext_vector_type(8)));
typedef float  floatx4 __attribute__((ext_vector_type(4)));

__device__ __forceinline__ unsigned pk2(unsigned lo, unsigned hi) {
  return (lo >> 16) | (hi & 0xffff0000u);
}

__device__ __forceinline__ bf16x8 asbf8(uint4 u) { bf16x8 v; __builtin_memcpy(&v, &u, 16); return v; }

// exact 3-way bf16 truncation split of 8 floats: f = H + M + L exactly
__device__ __forceinline__ void split3(float4 a, float4 b, uint4* H, uint4* M, uint4* L) {
  float f[8] = {a.x, a.y, a.z, a.w, b.x, b.y, b.z, b.w};
  unsigned h[8], m[8], l[8];
#pragma unroll
  for (int j = 0; j < 8; ++j) {
    union { float F; unsigned U; } u; u.F = f[j];
    h[j] = u.U & 0xffff0000u;
    union { unsigned U; float F; } hv; hv.U = h[j];
    float r1 = f[j] - hv.F;                 // exact
    union { float F; unsigned U; } r1u; r1u.F = r1;
    m[j] = r1u.U & 0xffff0000u;
    union { unsigned U; float F; } mv; mv.U = m[j];
    float r2 = r1 - mv.F;                   // exact, fits bf16
    union { float F; unsigned U; } r2u; r2u.F = r2;
    l[j] = r2u.U;
  }
  H->x = pk2(h[0], h[1]); H->y = pk2(h[2], h[3]); H->z = pk2(h[4], h[5]); H->w = pk2(h[6], h[7]);
  M->x = pk2(m[0], m[1]); M->y = pk2(m[2], m[3]); M->z = pk2(m[4], m[5]); M->w = pk2(m[6], m[7]);
  L->x = pk2(l[0], l[1]); L->y = pk2(l[2], l[3]); L->z = pk2(l[4], l[5]); L->w = pk2(l[6], l[7]);
}

#define GLDS16(g, l) __builtin_amdgcn_global_load_lds( \
    (const __attribute__((address_space(1))) unsigned int*)(g), \
    (__attribute__((address_space(3))) unsigned int*)(l), 16, 0, 0)

// ---------------- fused prep: gate (16 tok/block) + We fp32->bf16 cvt ----------------
// 2048 gate blocks (16 tokens each) + 2048 cvt blocks appended. Gate: no Wg LDS staging
// (B-frags split3'd from global Wg, 32KB L2-hot, bit-identical math); LDS = 5KB
// reduction buffer only. cvt blocks overlap the gate's tail.
__global__ __launch_bounds__(256, 4) void fused_prep(const float* __restrict__ x,
                                                     const float* __restrict__ Wg,
                                                     const float* __restrict__ bg,
                                                     const float* __restrict__ We,
                                                     int* __restrict__ counts,
                                                     int* __restrict__ buckets,
                                                     unsigned short* __restrict__ xbf,
                                                     unsigned short* __restrict__ webf) {
  __shared__ __align__(16) float red[4][16][20];   // [wave][token][expert], stride 20

  int bid = blockIdx.x;
  int t = threadIdx.x;

  if (bid >= GATE_BLKS) {
    // ---- We cvt block: 8 floats/thread, contiguous ----
    int i = (bid - GATE_BLKS) * 256 + t;
    const float4* src = (const float4*)We;
    float4 a = src[2 * i];
    float4 b = src[2 * i + 1];
    union { float F; unsigned U; } u[8] = {{a.x},{a.y},{a.z},{a.w},{b.x},{b.y},{b.z},{b.w}};
    uint4 o;
    o.x = pk2(u[0].U, u[1].U); o.y = pk2(u[2].U, u[3].U);
    o.z = pk2(u[4].U, u[5].U); o.w = pk2(u[6].U, u[7].U);
    ((uint4*)webf)[i] = o;
    return;
  }

  // ---- gate block: 16 tokens ----
  int lane = t & 63;
  int w = t >> 6;               // wave w covers k-range [w*128, w*128+128)
  int tok0 = bid * 16;
  int fr = lane & 15;           // A: token row; B: expert column
  int quad = lane >> 4;         // 8-float chunk within the 32-float k-step

  const float* xb0 = x + (size_t)(tok0 + fr) * HDIM + w * 128 + quad * 8;
  const float* wg0 = Wg + (size_t)fr * HDIM + w * 128 + quad * 8;

  floatx4 acc = {};

  // prefetch si=0 x
  float4 xa = *(const float4*)(xb0);
  float4 xv = *(const float4*)(xb0 + 4);

#pragma unroll
  for (int si = 0; si < 4; ++si) {
    int s = w * 4 + si;
    // B-frags from global (L2-hot 32KB), split in registers — bit-identical to staged path
    float4 wa = *(const float4*)(wg0 + si * 32);
    float4 wb = *(const float4*)(wg0 + si * 32 + 4);
    uint4 BH, BM, BL;
    split3(wa, wb, &BH, &BM, &BL);
    bf16x8 bh = asbf8(BH), bm = asbf8(BM), bl = asbf8(BL);

    float4 nxa, nxv;
    if (si < 3) {
      nxa = *(const float4*)(xb0 + (si + 1) * 32);
      nxv = *(const float4*)(xb0 + (si + 1) * 32 + 4);
    }

    uint4 H, M, L;
    split3(xa, xv, &H, &M, &L);
    *(uint4*)(xbf + (size_t)(tok0 + fr) * HDIM + s * 32 + quad * 8) = H;  // fused x->bf16
    bf16x8 ah = asbf8(H), am = asbf8(M), al = asbf8(L);
    acc = __builtin_amdgcn_mfma_f32_16x16x32_bf16(ah, bh, acc, 0, 0, 0);
    acc = __builtin_amdgcn_mfma_f32_16x16x32_bf16(ah, bm, acc, 0, 0, 0);
    acc = __builtin_amdgcn_mfma_f32_16x16x32_bf16(am, bh, acc, 0, 0, 0);
    acc = __builtin_amdgcn_mfma_f32_16x16x32_bf16(am, bm, acc, 0, 0, 0);
    acc = __builtin_amdgcn_mfma_f32_16x16x32_bf16(ah, bl, acc, 0, 0, 0);
    acc = __builtin_amdgcn_mfma_f32_16x16x32_bf16(al, bh, acc, 0, 0, 0);
    acc = __builtin_amdgcn_mfma_f32_16x16x32_bf16(am, bl, acc, 0, 0, 0);
    acc = __builtin_amdgcn_mfma_f32_16x16x32_bf16(al, bm, acc, 0, 0, 0);

    if (si < 3) { xa = nxa; xv = nxv; }
  }

  // cross-wave reduction: C/D layout col(lane&15)=expert, row=quad*4+i=token
#pragma unroll
  for (int i = 0; i < 4; ++i)
    red[w][quad * 4 + i][fr] = acc[i];
  __syncthreads();

  if (t < 16) {
    int r = t;    // token row
    float4 tot4[4];
#pragma unroll
    for (int eq = 0; eq < 4; ++eq) tot4[eq] = *(const float4*)&bg[eq * 4];
#pragma unroll
    for (int ww = 0; ww < 4; ++ww)
#pragma unroll
      for (int eq = 0; eq < 4; ++eq) {
        float4 v = *(const float4*)&red[ww][r][eq * 4];
        tot4[eq].x += v.x; tot4[eq].y += v.y; tot4[eq].z += v.z; tot4[eq].w += v.w;
      }
    float tot[16];
#pragma unroll
    for (int eq = 0; eq < 4; ++eq) {
      tot[eq * 4 + 0] = tot4[eq].x; tot[eq * 4 + 1] = tot4[eq].y;
      tot[eq * 4 + 2] = tot4[eq].z; tot[eq * 4 + 3] = tot4[eq].w;
    }
    float bv = tot[0]; int bi = 0;
#pragma unroll
    for (int e = 1; e < NEXP; ++e) if (tot[e] > bv) { bv = tot[e]; bi = e; }  // numpy first-index tie-break

    int token = tok0 + r;
    // staggered expert order: blocks hit different counters at any instant
    for (int ee = 0; ee < NEXP; ++ee) {
      int e = (ee + bid) & 15;
      unsigned long long mask = __ballot(bi == e);   // only lanes t<16 active
      if (mask) {
        int leader = __builtin_ctzll(mask);
        int base = 0;
        if (lane == leader) base = atomicAdd(&counts[e << 5], (int)__popcll(mask));
        base = __shfl(base, leader, 64);
        if (bi == e) {
          int rank = (int)__popcll(mask & ((1ull << lane) - 1ull));
          buckets[e * NTOK + base + rank] = token;
        }
      }
    }
  }
}

// ---------------- gathered-A GEMM, R8-exact (best: ~49us) ----------------
// 4096 blocks, bijective XCD swizzle: swz = (lin&7)*512 + (lin>>3) -> each XCD gets 512
// consecutive items = 2 full experts; expert working set (B 512KB + A ~2MB) fits the
// 4MB per-XCD L2 (verified: FETCH 53->29MB). One barrier per k-iter; glds for k+1
// issued after barrier k; explicit vmcnt(0) drain; 6 blocks/CU.
//
// LDS layout per R-row x 32 tile: cell(pair, slot), byte = pair*128 + slot*16,
// pair = row>>1, slot = (((row&1)<<2)|c) ^ (pair&7), c = 16B k-chunk. glds dest
// linear; inverse swizzle on the per-lane GLOBAL source (rule #21). Fragment
// ds_read_b128 = 2 lanes/bank (free, m136).
__global__ __launch_bounds__(256, 6) void moe_gemm(const unsigned short* __restrict__ xbf,
                                                   const unsigned short* __restrict__ webf,
                                                   const float* __restrict__ be,
                                                   const int* __restrict__ counts,
                                                   const int* __restrict__ buckets,
                                                   float* __restrict__ out) {
  int lin = blockIdx.x;
  int swz = (lin & 7) * 512 + (lin >> 3);   // XCD-contiguous work id (bijective, 4096%8==0)
  int e = swz >> 8;                          // 256 work items per expert
  int rem = swz & 255;
  int o0 = (rem >> 6) * TN;                  // 4 n-tiles
  int m0 = (rem & 63) * TM;                  // 64 m-tiles

  int cnt = counts[e << 5];
  if (m0 >= cnt) return;

  __shared__ __align__(16) unsigned short As[2][TM * BK];   // 2 x 4 KB
  __shared__ __align__(16) unsigned short Bs[2][TN * BK];   // 2 x 8 KB
  __shared__ int toks[TM];

  int t = threadIdx.x;
  int lane = t & 63;
  int w = t >> 6;

  if (t < TM) {
    int r = m0 + t;
    toks[t] = (r < cnt) ? buckets[e * NTOK + r] : buckets[e * NTOK];
  }
  __syncthreads();

  // staging decode: one glds covers 16 rows x 4 chunks = 64 lanes.
  int pl = lane >> 3;
  int sl = lane & 7;
  int slog = sl ^ pl;
  int rsub = 2 * pl + (slog >> 2);
  int cch = slog & 3;

  // A: wave w stages rows w*16 .. w*16+15 (1 glds)
  const unsigned short* agp = xbf + (size_t)toks[w * 16 + rsub] * HDIM + cch * 8;
  // B: wave w stages rows w*32+j*16 .. +15, j=0,1 (2 glds)
  const unsigned short* bgp[2];
#pragma unroll
  for (int j = 0; j < 2; ++j) {
    int row = w * 32 + j * 16 + rsub;
    bgp[j] = webf + ((size_t)e * ODIM + o0 + row) * HDIM + cch * 8;
  }

  int wm = (w & 1) * 32;        // 2 m-halves of 32
  int wn = (w >> 1) * 64;       // 2 n-halves of 64
  int fr = lane & 15;
  int quad = lane >> 4;

  int aoff[2], boff[4];
#pragma unroll
  for (int mt = 0; mt < 2; ++mt) {
    int m = wm + mt * 16 + fr;
    int pr = m >> 1;
    aoff[mt] = pr * 64 + (((((m & 1) << 2) | quad) ^ (pr & 7)) << 3);
  }
#pragma unroll
  for (int nt = 0; nt < 4; ++nt) {
    int n = wn + nt * 16 + fr;
    int pn = n >> 1;
    boff[nt] = pn * 64 + (((((n & 1) << 2) | quad) ^ (pn & 7)) << 3);
  }

  // hoist bias loads: complete long before the epilogue needs them
  float bias[4];
#pragma unroll
  for (int nt = 0; nt < 4; ++nt)
    bias[nt] = be[e * ODIM + o0 + wn + nt * 16 + fr];

  floatx4 acc[2][4] = {};

  // prologue: fill buffer 0 (k=0)
  GLDS16(agp, As[0] + w * 512);
#pragma unroll
  for (int j = 0; j < 2; ++j)
    GLDS16(bgp[j], Bs[0] + w * 1024 + j * 512);

  for (int k = 0; k < HDIM / BK; ++k) {
    int p = k & 1;
    // explicit drain: all of this wave's outstanding glds writes landed in LDS
    asm volatile("s_waitcnt vmcnt(0)" ::: "memory");
    __syncthreads();   // buf p ready everywhere; buf 1-p reads (iter k-1) done
    if (k < HDIM / BK - 1) {
      int koff = (k + 1) * BK;
      GLDS16(agp + koff, As[1 - p] + w * 512);
#pragma unroll
      for (int j = 0; j < 2; ++j)
        GLDS16(bgp[j] + koff, Bs[1 - p] + w * 1024 + j * 512);
    }

    bf16x8 af[2], bfr[4];
#pragma unroll
    for (int mt = 0; mt < 2; ++mt)
      af[mt] = *(const bf16x8*)(As[p] + aoff[mt]);
#pragma unroll
    for (int nt = 0; nt < 4; ++nt)
      bfr[nt] = *(const bf16x8*)(Bs[p] + boff[nt]);
#pragma unroll
    for (int mt = 0; mt < 2; ++mt)
#pragma unroll
      for (int nt = 0; nt < 4; ++nt)
        acc[mt][nt] = __builtin_amdgcn_mfma_f32_16x16x32_bf16(af[mt], bfr[nt], acc[mt][nt], 0, 0, 0);
  }

  // epilogue: C/D layout col=lane&15, row=quad*4+i
  int rbase = wm + quad * 4;
#pragma unroll
  for (int nt = 0; nt < 4; ++nt) {
    int col = o0 + wn + nt * 16 + fr;
#pragma unroll
    for (int mt = 0; mt < 2; ++mt) {
#pragma unroll
      for (int i = 0; i < 4; ++i) {
        int rl = rbase + mt * 16 + i;
        if (m0 + rl < cnt) {
          out[(size_t)toks[rl] * ODIM + col] = acc[mt][nt][i] + bias[nt];
        }
      }
    }
  }
}

// ---------------- launch ----------------
// ws layout: [0, 2KB) strided counts | [4KB, +2MB) buckets | xbf 32MB | webf 8MB
#define WS_BUCKETS 4096
#define WS_XBF (WS_BUCKETS + NEXP * NTOK * 4)
#define WS_WEBF (WS_XBF + NTOK * HDIM * 2)

extern "C" void kernel_launch(void* const* d_in, const int* in_sizes, int n_in,
                              void* d_out, int out_size, void* d_ws, size_t ws_size,
                              hipStream_t stream) {
  const float* x  = (const float*)d_in[0];
  const float* Wg = (const float*)d_in[1];
  const float* bg = (const float*)d_in[2];
  const float* We = (const float*)d_in[3];
  const float* be = (const float*)d_in[4];
  float* out = (float*)d_out;
  char* ws = (char*)d_ws;

  int* counts = (int*)ws;
  int* buckets = (int*)(ws + WS_BUCKETS);
  unsigned short* xbf  = (unsigned short*)(ws + WS_XBF);
  unsigned short* webf = (unsigned short*)(ws + WS_WEBF);

  (void)hipMemsetAsync(counts, 0, NEXP * CSTRIDE * 4, stream);
  fused_prep<<<GATE_BLKS + CVT_BLKS, 256, 0, stream>>>(x, Wg, bg, We, counts, buckets, xbf, webf);
  moe_gemm<<<MTILES * (ODIM / TN) * NEXP, 256, 0, stream>>>(xbf, webf, be, counts, buckets, out);
}